// Round 8
// baseline (254.121 us; speedup 1.0000x reference)
//
#include <hip/hip_runtime.h>

#define NBINS 2048
#define B 4
#define C 16
#define HID 32
#define NI 32
#define INTER 36864           // 192*192 interior pixels per image
#define PADMULT 28672         // 256*256 - 192*192 padded pixels per instance
#define EPSF 1e-6f
#define THR 256
#define BPI 72                // blocks per image
#define PPB 512               // pixels per block (72*512 == INTER)
#define NBLK (B * BPI)        // 288 blocks: 2/CU needs 57KB LDS + 8 waves ->
                              // co-resident under ANY occupancy calc; barrier
                              // cannot deadlock.

// ---- ws layout (uint units)
#define OFF_COUNTS 0                      // [B][NI] float
#define OFF_CSUMS  (OFF_COUNTS + B*NI)    // [B][NI][C] float
#define OFF_V      (OFF_CSUMS + B*NI*C)   // [B][NI][HID] float
#define OFF_PERR   (OFF_V + B*NI*HID)     // [B][NI] float
#define OFF_MINK   (OFF_PERR + B*NI)      // [B] uint (mapped float, min)
#define OFF_MAXK   (OFF_MINK + B)         // [B] uint (mapped float, max)
#define OFF_VMAX   (OFF_MAXK + B)         // [B][HID] float
#define CTRL_END   (OFF_VMAX + B*HID)     // 6536
#define OFF_BAR    8064                   // 4 barriers x 16 words (64B apart)
#define OFF_HCNT   8192                   // [NBLK][NBINS] packed cnt|pos<<16
#define WS_UINTS   (OFF_HCNT + NBLK*NBINS)  // ~2.4 MB

__device__ inline unsigned fmap(float f) {
    unsigned u = __float_as_uint(f);
    return (u & 0x80000000u) ? ~u : (u | 0x80000000u);
}
__device__ inline float funmap(unsigned k) {
    return (k & 0x80000000u) ? __uint_as_float(k & 0x7fffffffu)
                             : __uint_as_float(~k);
}

// Grid barrier on plain launches. __threadfence() (device-scope) before the
// arrive publishes this block's writes; after the spin it makes all other
// blocks' writes visible (handles cross-XCD L2 non-coherence).
// NOTE: __hip_atomic_fence does not exist on this ROCm's clang (round-7
// compile error); __threadfence is the portable equivalent.
__device__ inline void gbar(unsigned* bar, int idx) {
    __syncthreads();
    if (threadIdx.x == 0) {
        __threadfence();
        __hip_atomic_fetch_add(&bar[idx * 16], 1u, __ATOMIC_RELAXED,
                               __HIP_MEMORY_SCOPE_AGENT);
        while (__hip_atomic_load(&bar[idx * 16], __ATOMIC_RELAXED,
                                 __HIP_MEMORY_SCOPE_AGENT) < (unsigned)NBLK) {
            __builtin_amdgcn_s_sleep(8);
        }
        __threadfence();
    }
    __syncthreads();
}

// Tiny init: zero control+barrier region, set min keys, zero out.
__global__ void k_init(unsigned* wsu, float* out) {
    int i = threadIdx.x;
    for (int j = i; j < OFF_HCNT; j += 256) wsu[j] = 0u;
    __syncthreads();
    if (i < B) wsu[OFF_MINK + i] = 0xFFFFFFFFu;
    if (i == 0) out[0] = 0.f;
}

union SM {
    struct { float cnt[NI]; float sum[NI * 17]; } ph1;   // stride 17: avoid
                                                         // 2-bank aliasing
    struct { float v[NI * HID]; } ph2;
    struct { unsigned bmin, bmax; } ph3;
    struct { unsigned h[NBINS]; } ph4;                   // 8 KB
    struct { unsigned cnt[NBINS], pos[NBINS];
             float sum[NBINS];
             unsigned pc[THR], pp[THR];
             double a[THR]; } ph5;                       // 28.7 KB max
};

__global__ __launch_bounds__(THR, 2) void k_mega(
        const float* __restrict__ emb, const float* __restrict__ wgt,
        const int* __restrict__ gt, const float* __restrict__ W1,
        const float* __restrict__ b1, const float* __restrict__ W2,
        const float* __restrict__ b2, float* ws, unsigned* wsu, float* out) {
    __shared__ SM sm;
    unsigned* bar = wsu + OFF_BAR;
    int tid = threadIdx.x;
    int bx = blockIdx.x;
    int img = bx / BPI;                   // block-uniform
    int bxl = bx - img * BPI;
    int qbase = bxl * PPB;                // pixel range [qbase, qbase+PPB)

    // ---- phase 1: weighted per-instance counts & embedding sums (LDS-local,
    // then global atomics into the init-zeroed control region)
    for (int i = tid; i < NI; i += THR) sm.ph1.cnt[i] = 0.f;
    for (int i = tid; i < NI * 17; i += THR) sm.ph1.sum[i] = 0.f;
    __syncthreads();
    #pragma unroll
    for (int it = 0; it < PPB / THR; ++it) {
        int q = qbase + it * THR + tid;
        int g = gt[img * INTER + q];
        if (g > 0 && g <= NI) {
            float wv = wgt[img * INTER + q];
            atomicAdd(&sm.ph1.cnt[g - 1], wv);
            const float* e = emb + (size_t)img * C * INTER + q;
            #pragma unroll
            for (int c = 0; c < C; c++)
                atomicAdd(&sm.ph1.sum[(g - 1) * 17 + c], e[c * INTER] * wv);
        }
    }
    __syncthreads();
    for (int i = tid; i < NI; i += THR)
        atomicAdd(&ws[OFF_COUNTS + img * NI + i], sm.ph1.cnt[i]);
    for (int i = tid; i < NI * C; i += THR) {
        int n = i / C, c = i - n * C;
        atomicAdd(&ws[OFF_CSUMS + (img * NI + n) * C + c], sm.ph1.sum[n * 17 + c]);
    }
    gbar(bar, 0);

    // ---- phase 2: centers -> v[n,k], vmax[k], pad errors (4 blocks active)
    if (bxl == 0) {
        for (int idx = tid; idx < NI * HID; idx += THR) {
            int n = idx >> 5, k = idx & 31;
            float cntv = ws[OFF_COUNTS + img * NI + n] + EPSF;
            float acc = b1[k];
            #pragma unroll
            for (int c = 0; c < C; c++)
                acc += (ws[OFF_CSUMS + (img * NI + n) * C + c] / cntv) * W1[c * HID + k];
            sm.ph2.v[idx] = acc;
            ws[OFF_V + img * NI * HID + idx] = acc;
        }
        __syncthreads();
        if (tid < HID) {
            float m = -1e30f;
            #pragma unroll
            for (int n = 0; n < NI; n++) m = fmaxf(m, sm.ph2.v[n * HID + tid]);
            ws[OFF_VMAX + img * HID + tid] = m;
        }
        if (tid < NI) {
            float lg = b2[0];
            #pragma unroll
            for (int k = 0; k < HID; k++)
                lg += fmaxf(sm.ph2.v[tid * HID + k], 0.f) * W2[k];
            float pe = 1.f + lg;          // label = 0 in padding
            ws[OFF_PERR + img * NI + tid] = pe;
            unsigned key = fmap(pe);
            atomicMin(&wsu[OFF_MINK + img], key);
            atomicMax(&wsu[OFF_MAXK + img], key);
        }
    }
    gbar(bar, 1);

    // ---- phase 3: analytic per-pixel error bound (O(HID)/pixel)
    {
        if (tid == 0) { sm.ph3.bmin = 0xFFFFFFFFu; sm.ph3.bmax = 0u; }
        __syncthreads();
        const float* vmax = ws + OFF_VMAX + img * HID;   // wave-uniform
        float b2v = b2[0];
        float lmin = 1e30f, lmax = -1e30f;
        #pragma unroll
        for (int it = 0; it < PPB / THR; ++it) {
            int q = qbase + it * THR + tid;
            const float* ep = emb + (size_t)img * C * INTER + q;
            float u[HID];
            #pragma unroll
            for (int k = 0; k < HID; k++) u[k] = 0.f;
            #pragma unroll
            for (int c = 0; c < C; c++) {
                float ev = ep[c * INTER];
                #pragma unroll
                for (int k = 0; k < HID; k++) u[k] = fmaf(ev, W1[c * HID + k], u[k]);
            }
            float hi = b2v, lo = b2v;
            #pragma unroll
            for (int k = 0; k < HID; k++) {
                float t = fmaxf(vmax[k] - u[k], 0.f);
                float w = W2[k];
                hi = fmaf(fmaxf(w, 0.f), t, hi);
                lo = fmaf(fminf(w, 0.f), t, lo);
            }
            lmin = fminf(lmin, fminf(1.f - hi, 1.f + lo));
            lmax = fmaxf(lmax, fmaxf(1.f - lo, 1.f + hi));
        }
        atomicMin(&sm.ph3.bmin, fmap(lmin));
        atomicMax(&sm.ph3.bmax, fmap(lmax));
        __syncthreads();
        if (tid == 0) {
            atomicMin(&wsu[OFF_MINK + img], sm.ph3.bmin);
            atomicMax(&wsu[OFF_MAXK + img], sm.ph3.bmax);
        }
    }
    gbar(bar, 2);

    // ---- phase 4: LDS histogram, flushed with plain stores
    for (int i = tid; i < NBINS; i += THR) sm.ph4.h[i] = 0u;
    __syncthreads();
    {
        float emax = funmap(wsu[OFF_MAXK + img]);
        float emin = funmap(wsu[OFF_MINK + img]);
        float invbw = (float)NBINS / fmaxf(emax - emin, 1e-20f);
        float b2v = b2[0];
        const float* vimg = ws + OFF_V + img * NI * HID;  // wave-uniform
        #pragma unroll
        for (int it = 0; it < PPB / THR; ++it) {
            int q = qbase + it * THR + tid;
            const float* ep = emb + (size_t)img * C * INTER + q;
            float u[HID];
            #pragma unroll
            for (int k = 0; k < HID; k++) u[k] = 0.f;
            #pragma unroll
            for (int c = 0; c < C; c++) {
                float ev = ep[c * INTER];
                #pragma unroll
                for (int k = 0; k < HID; k++) u[k] = fmaf(ev, W1[c * HID + k], u[k]);
            }
            int g = gt[img * INTER + q];
            for (int n = 0; n < NI; n++) {
                const float* vn = vimg + n * HID;
                float lg0 = b2v, lg1 = 0.f, lg2 = 0.f, lg3 = 0.f;
                #pragma unroll
                for (int k = 0; k < HID; k += 4) {
                    lg0 = fmaf(fmaxf(vn[k + 0] - u[k + 0], 0.f), W2[k + 0], lg0);
                    lg1 = fmaf(fmaxf(vn[k + 1] - u[k + 1], 0.f), W2[k + 1], lg1);
                    lg2 = fmaf(fmaxf(vn[k + 2] - u[k + 2], 0.f), W2[k + 2], lg2);
                    lg3 = fmaf(fmaxf(vn[k + 3] - u[k + 3], 0.f), W2[k + 3], lg3);
                }
                float lg = (lg0 + lg1) + (lg2 + lg3);
                bool pos = (g == n + 1);
                float err = pos ? (1.f - lg) : (1.f + lg);
                int bn = (int)((emax - err) * invbw);
                bn = bn < 0 ? 0 : (bn >= NBINS ? NBINS - 1 : bn);
                atomicAdd(&sm.ph4.h[bn], pos ? 0x10001u : 1u);  // cnt<=16384
            }
        }
    }
    __syncthreads();
    {
        unsigned* gc = wsu + OFF_HCNT + (size_t)bx * NBINS;
        for (int i = tid; i < NBINS; i += THR) gc[i] = sm.ph4.h[i];
    }
    gbar(bar, 3);

    // ---- phase 5: reduce partials + pad + prefix scan + Lovasz (4 blocks)
    if (bxl == 0) {
        const int T = THR, CHUNK = NBINS / T;  // 8
        float emax = funmap(wsu[OFF_MAXK + img]);
        float emin = funmap(wsu[OFF_MINK + img]);
        float bw = (emax - emin) / (float)NBINS;
        float invbw = (float)NBINS / fmaxf(emax - emin, 1e-20f);
        for (int i = tid; i < NBINS; i += T) {
            unsigned cnt = 0, pos = 0;
            for (int r = 0; r < BPI; r++) {
                unsigned pk = wsu[OFF_HCNT + (size_t)(img * BPI + r) * NBINS + i];
                cnt += pk & 0xFFFFu;
                pos += pk >> 16;
            }
            sm.ph5.cnt[i] = cnt;
            sm.ph5.pos[i] = pos;
            float center = emax - ((float)i + 0.5f) * bw;
            sm.ph5.sum[i] = (float)cnt * fmaxf(center, 0.f);
        }
        __syncthreads();
        // pad-region: exact error values, PADMULT each, label 0
        if (tid < NI) {
            float pe = ws[OFF_PERR + img * NI + tid];
            int bn = (int)((emax - pe) * invbw);
            bn = bn < 0 ? 0 : (bn >= NBINS ? NBINS - 1 : bn);
            atomicAdd(&sm.ph5.cnt[bn], (unsigned)PADMULT);
            atomicAdd(&sm.ph5.sum[bn], (float)PADMULT * fmaxf(pe, 0.f));
        }
        __syncthreads();
        unsigned ccnt = 0, cpos = 0;
        for (int j = 0; j < CHUNK; j++) {
            int bn = tid * CHUNK + j;
            ccnt += sm.ph5.cnt[bn]; cpos += sm.ph5.pos[bn];
        }
        sm.ph5.pc[tid] = ccnt; sm.ph5.pp[tid] = cpos;
        __syncthreads();
        for (int off = 1; off < T; off <<= 1) {
            unsigned ac = 0, ap = 0;
            if (tid >= off) { ac = sm.ph5.pc[tid - off]; ap = sm.ph5.pp[tid - off]; }
            __syncthreads();
            sm.ph5.pc[tid] += ac; sm.ph5.pp[tid] += ap;
            __syncthreads();
        }
        double Gd = (double)sm.ph5.pp[T - 1];
        double r = (double)(sm.ph5.pc[tid] - ccnt);
        double L = (double)(sm.ph5.pp[tid] - cpos);
        double Jprev = 1.0 - (Gd - L) / (Gd + r - L);
        double acc = 0.0;
        for (int j = 0; j < CHUNK; j++) {
            int bn = tid * CHUNK + j;
            unsigned cv = sm.ph5.cnt[bn], pv = sm.ph5.pos[bn];
            if (cv) {
                r += (double)cv; L += (double)pv;
                double J = 1.0 - (Gd - L) / (Gd + r - L);
                double mean = (double)sm.ph5.sum[bn] / (double)cv;
                acc += mean * (J - Jprev);
                Jprev = J;
            }
        }
        sm.ph5.a[tid] = acc;
        __syncthreads();
        for (int s = T / 2; s > 0; s >>= 1) {
            if (tid < s) sm.ph5.a[tid] += sm.ph5.a[tid + s];
            __syncthreads();
        }
        if (tid == 0) atomicAdd(out, (float)(sm.ph5.a[0] * 0.25));  // mean, B=4
    }
}

extern "C" void kernel_launch(void* const* d_in, const int* in_sizes, int n_in,
                              void* d_out, int out_size, void* d_ws, size_t ws_size,
                              hipStream_t stream) {
    const float* emb = (const float*)d_in[0];
    const float* wgt = (const float*)d_in[1];
    const int*   gt  = (const int*)d_in[2];
    const float* W1  = (const float*)d_in[3];
    const float* b1  = (const float*)d_in[4];
    const float* W2  = (const float*)d_in[5];
    const float* b2  = (const float*)d_in[6];
    float* out = (float*)d_out;
    float* ws  = (float*)d_ws;
    unsigned* wsu = (unsigned*)d_ws;

    k_init<<<1, 256, 0, stream>>>(wsu, out);
    k_mega<<<NBLK, THR, 0, stream>>>(emb, wgt, gt, W1, b1, W2, b2, ws, wsu, out);
}

// Round 9
// 202.311 us; speedup vs baseline: 1.2561x; 1.2561x over previous
//
#include <hip/hip_runtime.h>

#define NBINS 4096
#define B 4
#define C 16
#define HID 32
#define NI 32
#define INTER 36864           // 192*192 interior pixels per image
#define PADMULT 28672         // 256*256 - 192*192 padded pixels per instance
#define EPSF 1e-6f
#define THR 256
#define BPI 144               // blocks per image, 1 pixel/thread
#define NBLK (B * BPI)        // 576 free-running blocks (no co-residency req)
#define RED_BLKS 64           // kC: 16 reduce blocks per image

// ---- ws layout (uint units)
#define OFF_COUNTS 0                      // [B][NI] float
#define OFF_CSUMS  (OFF_COUNTS + B*NI)    // [B][NI][C] float
#define OFF_V      (OFF_CSUMS + B*NI*C)   // [B][NI][HID] float
#define OFF_PERR   (OFF_V + B*NI*HID)     // [B][NI] float
#define OFF_MKEY   (OFF_PERR + B*NI)      // [B] uint: fmap(max ||e||^2)
#define OFF_RANGE  (OFF_MKEY + B)         // [B][2] float: emin, emax
#define OFF_DONEA  (OFF_RANGE + 2*B)      // 1 uint arrival counter (kA)
#define OFF_DONEC  (OFF_DONEA + 1)        // [B] uint arrival counters (kC)
#define CTRL_END   (OFF_DONEC + B)
#define OFF_HCNT   8192                   // [NBLK][NBINS] packed cnt|pos<<16
#define OFF_FCNT   (OFF_HCNT + NBLK*NBINS)  // [B][NBINS]
#define OFF_FPOS   (OFF_FCNT + B*NBINS)     // [B][NBINS]

__device__ inline unsigned fmap(float f) {
    unsigned u = __float_as_uint(f);
    return (u & 0x80000000u) ? ~u : (u | 0x80000000u);
}
__device__ inline float funmap(unsigned k) {
    return (k & 0x80000000u) ? __uint_as_float(k & 0x7fffffffu)
                             : __uint_as_float(~k);
}

// Tiny init: zero control region (incl. done counters) + out.
__global__ void k_init(unsigned* wsu, float* out) {
    int i = threadIdx.x;
    for (int j = i; j < CTRL_END; j += 256) wsu[j] = 0u;
    if (i == 0) out[0] = 0.f;
}

// kA: per-instance counts & weighted embedding sums + global max ||e||^2.
// The LAST arriving block (done-counter; no spin, no co-residency needed)
// computes centers -> v[n,k], pad errors, and the analytic histogram range:
// |u_k| <= max||e|| * ||W1_k|| (Cauchy-Schwarz) => lg in [lo_n, hi_n].
__global__ __launch_bounds__(THR, 4) void k_stats(
        const float* __restrict__ emb, const float* __restrict__ wgt,
        const int* __restrict__ gt, const float* __restrict__ W1,
        const float* __restrict__ b1, const float* __restrict__ W2,
        const float* __restrict__ b2, float* ws, unsigned* wsu) {
    __shared__ float s_cnt[NI];
    __shared__ float s_sum[NI * 17];   // stride 17: avoid 2-bank aliasing
    __shared__ unsigned s_mk;
    __shared__ int s_last;
    int tid = threadIdx.x, bx = blockIdx.x;
    int img = bx / BPI;
    int q = (bx - img * BPI) * THR + tid;
    for (int i = tid; i < NI; i += THR) s_cnt[i] = 0.f;
    for (int i = tid; i < NI * 17; i += THR) s_sum[i] = 0.f;
    if (tid == 0) s_mk = 0u;
    __syncthreads();

    int g = gt[img * INTER + q];
    const float* ep = emb + (size_t)img * C * INTER + q;
    float e[C];
    float nrm = 0.f;
    #pragma unroll
    for (int c = 0; c < C; c++) { e[c] = ep[c * INTER]; nrm = fmaf(e[c], e[c], nrm); }
    if (g > 0) {
        float wv = wgt[img * INTER + q];
        atomicAdd(&s_cnt[g - 1], wv);
        #pragma unroll
        for (int c = 0; c < C; c++)
            atomicAdd(&s_sum[(g - 1) * 17 + c], e[c] * wv);
    }
    atomicMax(&s_mk, fmap(nrm));
    __syncthreads();
    for (int i = tid; i < NI; i += THR)
        atomicAdd(&ws[OFF_COUNTS + img * NI + i], s_cnt[i]);
    for (int i = tid; i < NI * C; i += THR) {
        int n = i / C, c = i - n * C;
        atomicAdd(&ws[OFF_CSUMS + (img * NI + n) * C + c], s_sum[n * 17 + c]);
    }
    if (tid == 0) atomicMax(&wsu[OFF_MKEY + img], s_mk);
    __threadfence();
    if (tid == 0)
        s_last = (atomicAdd(&wsu[OFF_DONEA], 1u) == (unsigned)(NBLK - 1));
    __syncthreads();
    if (!s_last) return;
    __threadfence();   // acquire: see all blocks' atomics

    // ---- finalize (one block, ~1-2 us): v, perr, range for all images
    __shared__ float s_v[NI * HID];
    __shared__ float s_a[HID];
    __shared__ unsigned s_lo, s_hi;
    float b2v = b2[0];
    for (int im = 0; im < B; ++im) {
        float M = sqrtf(funmap(wsu[OFF_MKEY + im]));
        if (tid < HID) {
            float ssq = 0.f;
            #pragma unroll
            for (int c = 0; c < C; c++)
                ssq = fmaf(W1[c * HID + tid], W1[c * HID + tid], ssq);
            s_a[tid] = M * sqrtf(ssq);
        }
        for (int idx = tid; idx < NI * HID; idx += THR) {
            int n = idx >> 5, k = idx & 31;
            float cv = ws[OFF_COUNTS + im * NI + n] + EPSF;
            float acc = b1[k];
            #pragma unroll
            for (int c = 0; c < C; c++)
                acc += (ws[OFF_CSUMS + (im * NI + n) * C + c] / cv) * W1[c * HID + k];
            s_v[idx] = acc;
            ws[OFF_V + im * NI * HID + idx] = acc;
        }
        if (tid == 0) { s_lo = 0xFFFFFFFFu; s_hi = 0u; }
        __syncthreads();
        if (tid < NI) {
            float lo = b2v, hi = b2v, lgp = b2v;
            #pragma unroll
            for (int k = 0; k < HID; k++) {
                float vk = s_v[tid * HID + k], a = s_a[k], w = W2[k];
                float thi = fmaxf(vk + a, 0.f), tlo = fmaxf(vk - a, 0.f);
                hi += w * (w > 0.f ? thi : tlo);
                lo += w * (w > 0.f ? tlo : thi);
                lgp = fmaf(fmaxf(vk, 0.f), w, lgp);   // pad: u = 0 (exact)
            }
            float pe = 1.f + lgp;
            ws[OFF_PERR + im * NI + tid] = pe;
            atomicMin(&s_lo, fmap(fminf(1.f - hi, 1.f + lo)));
            atomicMax(&s_hi, fmap(fmaxf(1.f - lo, 1.f + hi)));
        }
        __syncthreads();
        if (tid == 0) {
            ((float*)wsu)[OFF_RANGE + im * 2]     = funmap(s_lo);
            ((float*)wsu)[OFF_RANGE + im * 2 + 1] = funmap(s_hi);
        }
        __syncthreads();   // before s_v reuse next image
    }
}

// kB: LDS histogram per block (free-running, 576 blocks), plain-store flush.
// v/W1/W2 via wave-uniform scalar loads; packed cnt|pos<<16 (<=8192/block).
__global__ __launch_bounds__(THR, 4) void k_hist(
        const float* __restrict__ emb, const int* __restrict__ gt,
        const float* __restrict__ W1, const float* __restrict__ W2,
        const float* __restrict__ b2, const float* __restrict__ ws,
        unsigned* wsu) {
    __shared__ unsigned s_h[NBINS];   // 16 KB
    int tid = threadIdx.x, bx = blockIdx.x;
    int img = bx / BPI;
    int q = (bx - img * BPI) * THR + tid;
    for (int i = tid; i < NBINS; i += THR) s_h[i] = 0u;
    float emin = ((const float*)wsu)[OFF_RANGE + img * 2];
    float emax = ((const float*)wsu)[OFF_RANGE + img * 2 + 1];
    float invbw = (float)NBINS / fmaxf(emax - emin, 1e-20f);
    float b2v = b2[0];
    const float* vimg = ws + OFF_V + img * NI * HID;   // wave-uniform
    __syncthreads();

    const float* ep = emb + (size_t)img * C * INTER + q;
    float u[HID];
    #pragma unroll
    for (int k = 0; k < HID; k++) u[k] = 0.f;
    #pragma unroll
    for (int c = 0; c < C; c++) {
        float ev = ep[c * INTER];
        #pragma unroll
        for (int k = 0; k < HID; k++) u[k] = fmaf(ev, W1[c * HID + k], u[k]);
    }
    int g = gt[img * INTER + q];
    for (int n = 0; n < NI; n++) {
        const float* vn = vimg + n * HID;
        float lg0 = b2v, lg1 = 0.f, lg2 = 0.f, lg3 = 0.f;
        #pragma unroll
        for (int k = 0; k < HID; k += 4) {
            lg0 = fmaf(fmaxf(vn[k + 0] - u[k + 0], 0.f), W2[k + 0], lg0);
            lg1 = fmaf(fmaxf(vn[k + 1] - u[k + 1], 0.f), W2[k + 1], lg1);
            lg2 = fmaf(fmaxf(vn[k + 2] - u[k + 2], 0.f), W2[k + 2], lg2);
            lg3 = fmaf(fmaxf(vn[k + 3] - u[k + 3], 0.f), W2[k + 3], lg3);
        }
        float lg = (lg0 + lg1) + (lg2 + lg3);
        bool pos = (g == n + 1);
        float err = pos ? (1.f - lg) : (1.f + lg);
        int bn = (int)((emax - err) * invbw);
        bn = bn < 0 ? 0 : (bn >= NBINS ? NBINS - 1 : bn);
        atomicAdd(&s_h[bn], pos ? 0x10001u : 1u);
    }
    __syncthreads();
    unsigned* gc = wsu + OFF_HCNT + (size_t)bx * NBINS;
    for (int i = tid; i < NBINS; i += THR) gc[i] = s_h[i];
}

// kC: 64 blocks reduce the partials (16 blocks/image, coalesced); the last
// block per image (done-counter) runs the Lovasz scan in double precision.
__global__ void k_finish(const float* ws, unsigned* wsu, float* out) {
    int tid = threadIdx.x, b = blockIdx.x;
    int img = b >> 4;
    int bin0 = (b & 15) * 256 + tid;          // 1 bin per thread
    unsigned cnt = 0, pos = 0;
    for (int r = 0; r < BPI; r++) {
        unsigned pk = wsu[OFF_HCNT + (size_t)(img * BPI + r) * NBINS + bin0];
        cnt += pk & 0xFFFFu;
        pos += pk >> 16;
    }
    wsu[OFF_FCNT + img * NBINS + bin0] = cnt;
    wsu[OFF_FPOS + img * NBINS + bin0] = pos;
    __threadfence();
    __shared__ int s_last;
    if (tid == 0)
        s_last = (atomicAdd(&wsu[OFF_DONEC + img], 1u) == 15u);
    __syncthreads();
    if (!s_last) return;
    __threadfence();

    // ---- Lovasz scan for this image
    const int T = 256, CHUNK = NBINS / T;     // 16
    __shared__ unsigned s_cnt[NBINS], s_pos[NBINS];  // 32 KB
    __shared__ float s_sum[NBINS];                   // 16 KB
    __shared__ unsigned s_pc[T], s_pp[T];
    __shared__ double s_a[T];
    float emin = ((const float*)wsu)[OFF_RANGE + img * 2];
    float emax = ((const float*)wsu)[OFF_RANGE + img * 2 + 1];
    float bw = (emax - emin) / (float)NBINS;
    float invbw = (float)NBINS / fmaxf(emax - emin, 1e-20f);
    for (int i = tid; i < NBINS; i += T) {
        unsigned cv = wsu[OFF_FCNT + img * NBINS + i];
        s_cnt[i] = cv;
        s_pos[i] = wsu[OFF_FPOS + img * NBINS + i];
        float center = emax - ((float)i + 0.5f) * bw;
        s_sum[i] = (float)cv * fmaxf(center, 0.f);
    }
    __syncthreads();
    // pad-region: exact error values, PADMULT each, label 0
    if (tid < NI) {
        float pe = ws[OFF_PERR + img * NI + tid];
        int bn = (int)((emax - pe) * invbw);
        bn = bn < 0 ? 0 : (bn >= NBINS ? NBINS - 1 : bn);
        atomicAdd(&s_cnt[bn], (unsigned)PADMULT);
        atomicAdd(&s_sum[bn], (float)PADMULT * fmaxf(pe, 0.f));
    }
    __syncthreads();
    unsigned ccnt = 0, cpos = 0;
    for (int j = 0; j < CHUNK; j++) {
        int bn = tid * CHUNK + j;
        ccnt += s_cnt[bn]; cpos += s_pos[bn];
    }
    s_pc[tid] = ccnt; s_pp[tid] = cpos;
    __syncthreads();
    for (int off = 1; off < T; off <<= 1) {
        unsigned ac = 0, ap = 0;
        if (tid >= off) { ac = s_pc[tid - off]; ap = s_pp[tid - off]; }
        __syncthreads();
        s_pc[tid] += ac; s_pp[tid] += ap;
        __syncthreads();
    }
    double Gd = (double)s_pp[T - 1];
    double r = (double)(s_pc[tid] - ccnt);
    double L = (double)(s_pp[tid] - cpos);
    double Jprev = 1.0 - (Gd - L) / (Gd + r - L);
    double acc = 0.0;
    for (int j = 0; j < CHUNK; j++) {
        int bn = tid * CHUNK + j;
        unsigned cv = s_cnt[bn], pv = s_pos[bn];
        if (cv) {
            r += (double)cv; L += (double)pv;
            double J = 1.0 - (Gd - L) / (Gd + r - L);
            double mean = (double)s_sum[bn] / (double)cv;
            acc += mean * (J - Jprev);
            Jprev = J;
        }
    }
    s_a[tid] = acc;
    __syncthreads();
    for (int s = T / 2; s > 0; s >>= 1) {
        if (tid < s) s_a[tid] += s_a[tid + s];
        __syncthreads();
    }
    if (tid == 0) atomicAdd(out, (float)(s_a[0] * 0.25));  // mean over B=4
}

extern "C" void kernel_launch(void* const* d_in, const int* in_sizes, int n_in,
                              void* d_out, int out_size, void* d_ws, size_t ws_size,
                              hipStream_t stream) {
    const float* emb = (const float*)d_in[0];
    const float* wgt = (const float*)d_in[1];
    const int*   gt  = (const int*)d_in[2];
    const float* W1  = (const float*)d_in[3];
    const float* b1  = (const float*)d_in[4];
    const float* W2  = (const float*)d_in[5];
    const float* b2  = (const float*)d_in[6];
    float* out = (float*)d_out;
    float* ws  = (float*)d_ws;
    unsigned* wsu = (unsigned*)d_ws;

    k_init<<<1, 256, 0, stream>>>(wsu, out);
    k_stats<<<NBLK, THR, 0, stream>>>(emb, wgt, gt, W1, b1, W2, b2, ws, wsu);
    k_hist<<<NBLK, THR, 0, stream>>>(emb, gt, W1, W2, b2, ws, wsu);
    k_finish<<<RED_BLKS, 256, 0, stream>>>(ws, wsu, out);
}

// Round 10
// 145.478 us; speedup vs baseline: 1.7468x; 1.3907x over previous
//
#include <hip/hip_runtime.h>

#define NBINS 4096
#define B 4
#define C 16
#define HID 32
#define NI 32
#define INTER 36864           // 192*192 interior pixels per image
#define PADMULT 28672         // 256*256 - 192*192 padded pixels per instance
#define EPSF 1e-6f
#define THR 256
#define BPI 144               // blocks per image, 1 pixel/thread
#define NBLK (B * BPI)        // 576 free-running blocks

// ---- ws layout (uint units)
#define OFF_COUNTS 0                      // [B][NI] float
#define OFF_CSUMS  (OFF_COUNTS + B*NI)    // [B][NI][C] float
#define OFF_V      (OFF_CSUMS + B*NI*C)   // [B][NI][HID] float
#define OFF_PERR   (OFF_V + B*NI*HID)     // [B][NI] float
#define OFF_MKEY   (OFF_PERR + B*NI)      // [B] uint: fmap(max ||e||^2)
#define OFF_RANGE  (OFF_MKEY + B)         // [B][2] float: emin, emax
#define CTRL_END   (OFF_RANGE + 2*B)
#define OFF_HCNT   8192                   // [NBLK][NBINS] packed cnt|pos<<16
#define OFF_FCNT   (OFF_HCNT + NBLK*NBINS)  // [B][NBINS]
#define OFF_FPOS   (OFF_FCNT + B*NBINS)     // [B][NBINS]

__device__ inline unsigned fmap(float f) {
    unsigned u = __float_as_uint(f);
    return (u & 0x80000000u) ? ~u : (u | 0x80000000u);
}
__device__ inline float funmap(unsigned k) {
    return (k & 0x80000000u) ? __uint_as_float(k & 0x7fffffffu)
                             : __uint_as_float(~k);
}

// Tiny init: zero control region + out. (Kernel boundaries provide all
// inter-kernel visibility -- NO __threadfence anywhere: round 9 showed
// per-block agent-scope fences cost ~80us on non-coherent per-XCD L2s.)
__global__ void k_init(unsigned* wsu, float* out) {
    int i = threadIdx.x;
    if (i < CTRL_END) wsu[i] = 0u;
    if (i == 0) out[0] = 0.f;
}

// k_stats: per-instance counts & weighted embedding sums + max ||e||^2.
// Relaxed global atomics only (device-scope by default on gfx950).
__global__ __launch_bounds__(THR, 4) void k_stats(
        const float* __restrict__ emb, const float* __restrict__ wgt,
        const int* __restrict__ gt, float* ws, unsigned* wsu) {
    __shared__ float s_cnt[NI];
    __shared__ float s_sum[NI * 17];   // stride 17: avoid 2-bank aliasing
    __shared__ unsigned s_mk;
    int tid = threadIdx.x, bx = blockIdx.x;
    int img = bx / BPI;
    int q = (bx - img * BPI) * THR + tid;
    for (int i = tid; i < NI; i += THR) s_cnt[i] = 0.f;
    for (int i = tid; i < NI * 17; i += THR) s_sum[i] = 0.f;
    if (tid == 0) s_mk = 0u;
    __syncthreads();

    int g = gt[img * INTER + q];
    const float* ep = emb + (size_t)img * C * INTER + q;
    float e[C];
    float nrm = 0.f;
    #pragma unroll
    for (int c = 0; c < C; c++) { e[c] = ep[c * INTER]; nrm = fmaf(e[c], e[c], nrm); }
    if (g > 0) {
        float wv = wgt[img * INTER + q];
        atomicAdd(&s_cnt[g - 1], wv);
        #pragma unroll
        for (int c = 0; c < C; c++)
            atomicAdd(&s_sum[(g - 1) * 17 + c], e[c] * wv);
    }
    atomicMax(&s_mk, fmap(nrm));
    __syncthreads();
    for (int i = tid; i < NI; i += THR)
        atomicAdd(&ws[OFF_COUNTS + img * NI + i], s_cnt[i]);
    for (int i = tid; i < NI * C; i += THR) {
        int n = i / C, c = i - n * C;
        atomicAdd(&ws[OFF_CSUMS + (img * NI + n) * C + c], s_sum[n * 17 + c]);
    }
    if (tid == 0) atomicMax(&wsu[OFF_MKEY + img], s_mk);
}

// k_centers: one block per image. v[n,k] = centers.W1 + b1; pad errors
// (u=0 exactly); analytic histogram range via Cauchy-Schwarz:
// |u_k| <= max||e|| * ||W1_k|| => lg in [lo,hi] per instance.
__global__ void k_centers(const float* __restrict__ W1, const float* __restrict__ b1,
                          const float* __restrict__ W2, const float* __restrict__ b2,
                          float* ws, unsigned* wsu) {
    int im = blockIdx.x, tid = threadIdx.x;
    __shared__ float s_v[NI * HID];
    __shared__ float s_a[HID];
    __shared__ unsigned s_lo, s_hi;
    float b2v = b2[0];
    float M = sqrtf(funmap(wsu[OFF_MKEY + im]));
    if (tid < HID) {
        float ssq = 0.f;
        #pragma unroll
        for (int c = 0; c < C; c++)
            ssq = fmaf(W1[c * HID + tid], W1[c * HID + tid], ssq);
        s_a[tid] = M * sqrtf(ssq);
    }
    if (tid == 0) { s_lo = 0xFFFFFFFFu; s_hi = 0u; }
    for (int idx = tid; idx < NI * HID; idx += THR) {
        int n = idx >> 5, k = idx & 31;
        float cv = ws[OFF_COUNTS + im * NI + n] + EPSF;
        float acc = b1[k];
        #pragma unroll
        for (int c = 0; c < C; c++)
            acc += (ws[OFF_CSUMS + (im * NI + n) * C + c] / cv) * W1[c * HID + k];
        s_v[idx] = acc;
        ws[OFF_V + im * NI * HID + idx] = acc;
    }
    __syncthreads();
    if (tid < NI) {
        float lo = b2v, hi = b2v, lgp = b2v;
        #pragma unroll
        for (int k = 0; k < HID; k++) {
            float vk = s_v[tid * HID + k], a = s_a[k], w = W2[k];
            float thi = fmaxf(vk + a, 0.f), tlo = fmaxf(vk - a, 0.f);
            hi += w * (w > 0.f ? thi : tlo);
            lo += w * (w > 0.f ? tlo : thi);
            lgp = fmaf(fmaxf(vk, 0.f), w, lgp);   // pad pixels: u = 0 exact
        }
        float pe = 1.f + lgp;
        ws[OFF_PERR + im * NI + tid] = pe;
        atomicMin(&s_lo, fmap(fminf(1.f - hi, 1.f + lo)));
        atomicMax(&s_hi, fmap(fmaxf(1.f - lo, 1.f + hi)));
    }
    __syncthreads();
    if (tid == 0) {
        ((float*)wsu)[OFF_RANGE + im * 2]     = funmap(s_lo);
        ((float*)wsu)[OFF_RANGE + im * 2 + 1] = funmap(s_hi);
    }
}

// k_hist: LDS histogram per block (free-running), plain-store flush.
// v/W1/W2 via wave-uniform scalar loads; packed cnt|pos<<16 (<=8192/block).
__global__ __launch_bounds__(THR, 4) void k_hist(
        const float* __restrict__ emb, const int* __restrict__ gt,
        const float* __restrict__ W1, const float* __restrict__ W2,
        const float* __restrict__ b2, const float* __restrict__ ws,
        unsigned* wsu) {
    __shared__ unsigned s_h[NBINS];   // 16 KB
    int tid = threadIdx.x, bx = blockIdx.x;
    int img = bx / BPI;
    int q = (bx - img * BPI) * THR + tid;
    for (int i = tid; i < NBINS; i += THR) s_h[i] = 0u;
    float emin = ((const float*)wsu)[OFF_RANGE + img * 2];
    float emax = ((const float*)wsu)[OFF_RANGE + img * 2 + 1];
    float invbw = (float)NBINS / fmaxf(emax - emin, 1e-20f);
    float b2v = b2[0];
    const float* vimg = ws + OFF_V + img * NI * HID;   // wave-uniform
    __syncthreads();

    const float* ep = emb + (size_t)img * C * INTER + q;
    float u[HID];
    #pragma unroll
    for (int k = 0; k < HID; k++) u[k] = 0.f;
    #pragma unroll
    for (int c = 0; c < C; c++) {
        float ev = ep[c * INTER];
        #pragma unroll
        for (int k = 0; k < HID; k++) u[k] = fmaf(ev, W1[c * HID + k], u[k]);
    }
    int g = gt[img * INTER + q];
    for (int n = 0; n < NI; n++) {
        const float* vn = vimg + n * HID;
        float lg0 = b2v, lg1 = 0.f, lg2 = 0.f, lg3 = 0.f;
        #pragma unroll
        for (int k = 0; k < HID; k += 4) {
            lg0 = fmaf(fmaxf(vn[k + 0] - u[k + 0], 0.f), W2[k + 0], lg0);
            lg1 = fmaf(fmaxf(vn[k + 1] - u[k + 1], 0.f), W2[k + 1], lg1);
            lg2 = fmaf(fmaxf(vn[k + 2] - u[k + 2], 0.f), W2[k + 2], lg2);
            lg3 = fmaf(fmaxf(vn[k + 3] - u[k + 3], 0.f), W2[k + 3], lg3);
        }
        float lg = (lg0 + lg1) + (lg2 + lg3);
        bool pos = (g == n + 1);
        float err = pos ? (1.f - lg) : (1.f + lg);
        int bn = (int)((emax - err) * invbw);
        bn = bn < 0 ? 0 : (bn >= NBINS ? NBINS - 1 : bn);
        atomicAdd(&s_h[bn], pos ? 0x10001u : 1u);
    }
    __syncthreads();
    unsigned* gc = wsu + OFF_HCNT + (size_t)bx * NBINS;
    for (int i = tid; i < NBINS; i += THR) gc[i] = s_h[i];
}

// k_reduce: collapse the BPI partials per (img, bin). 64 blocks, coalesced.
__global__ void k_reduce(unsigned* wsu) {
    int tid = threadIdx.x, b = blockIdx.x;
    int img = b >> 4;
    int bn = (b & 15) * 256 + tid;            // 16 blocks/image * 256 = 4096
    unsigned cnt = 0, pos = 0;
    for (int r = 0; r < BPI; r++) {
        unsigned pk = wsu[OFF_HCNT + (size_t)(img * BPI + r) * NBINS + bn];
        cnt += pk & 0xFFFFu;
        pos += pk >> 16;
    }
    wsu[OFF_FCNT + img * NBINS + bn] = cnt;
    wsu[OFF_FPOS + img * NBINS + bn] = pos;
}

// k_loss: per-image -- bin-center sums, exact pad contributions, prefix
// scan, Lovasz loss in double precision, mean over B into out.
__global__ void k_loss(const float* ws, const unsigned* wsu, float* out) {
    const int T = 256, CHUNK = NBINS / T;     // 16
    int img = blockIdx.x, tid = threadIdx.x;
    __shared__ unsigned s_cnt[NBINS], s_pos[NBINS];  // 32 KB
    __shared__ float s_sum[NBINS];                   // 16 KB
    __shared__ unsigned s_pc[T], s_pp[T];
    __shared__ double s_a[T];
    float emin = ((const float*)wsu)[OFF_RANGE + img * 2];
    float emax = ((const float*)wsu)[OFF_RANGE + img * 2 + 1];
    float bw = (emax - emin) / (float)NBINS;
    float invbw = (float)NBINS / fmaxf(emax - emin, 1e-20f);
    for (int i = tid; i < NBINS; i += T) {
        unsigned cv = wsu[OFF_FCNT + img * NBINS + i];
        s_cnt[i] = cv;
        s_pos[i] = wsu[OFF_FPOS + img * NBINS + i];
        float center = emax - ((float)i + 0.5f) * bw;
        s_sum[i] = (float)cv * fmaxf(center, 0.f);
    }
    __syncthreads();
    // pad-region: exact error values, PADMULT each, label 0
    if (tid < NI) {
        float pe = ws[OFF_PERR + img * NI + tid];
        int bn = (int)((emax - pe) * invbw);
        bn = bn < 0 ? 0 : (bn >= NBINS ? NBINS - 1 : bn);
        atomicAdd(&s_cnt[bn], (unsigned)PADMULT);
        atomicAdd(&s_sum[bn], (float)PADMULT * fmaxf(pe, 0.f));
    }
    __syncthreads();
    unsigned ccnt = 0, cpos = 0;
    for (int j = 0; j < CHUNK; j++) {
        int bn = tid * CHUNK + j;
        ccnt += s_cnt[bn]; cpos += s_pos[bn];
    }
    s_pc[tid] = ccnt; s_pp[tid] = cpos;
    __syncthreads();
    for (int off = 1; off < T; off <<= 1) {
        unsigned ac = 0, ap = 0;
        if (tid >= off) { ac = s_pc[tid - off]; ap = s_pp[tid - off]; }
        __syncthreads();
        s_pc[tid] += ac; s_pp[tid] += ap;
        __syncthreads();
    }
    double Gd = (double)s_pp[T - 1];
    double r = (double)(s_pc[tid] - ccnt);
    double L = (double)(s_pp[tid] - cpos);
    double Jprev = 1.0 - (Gd - L) / (Gd + r - L);
    double acc = 0.0;
    for (int j = 0; j < CHUNK; j++) {
        int bn = tid * CHUNK + j;
        unsigned cv = s_cnt[bn], pv = s_pos[bn];
        if (cv) {
            r += (double)cv; L += (double)pv;
            double J = 1.0 - (Gd - L) / (Gd + r - L);
            double mean = (double)s_sum[bn] / (double)cv;
            acc += mean * (J - Jprev);
            Jprev = J;
        }
    }
    s_a[tid] = acc;
    __syncthreads();
    for (int s = T / 2; s > 0; s >>= 1) {
        if (tid < s) s_a[tid] += s_a[tid + s];
        __syncthreads();
    }
    if (tid == 0) atomicAdd(out, (float)(s_a[0] * 0.25));  // mean over B=4
}

extern "C" void kernel_launch(void* const* d_in, const int* in_sizes, int n_in,
                              void* d_out, int out_size, void* d_ws, size_t ws_size,
                              hipStream_t stream) {
    const float* emb = (const float*)d_in[0];
    const float* wgt = (const float*)d_in[1];
    const int*   gt  = (const int*)d_in[2];
    const float* W1  = (const float*)d_in[3];
    const float* b1  = (const float*)d_in[4];
    const float* W2  = (const float*)d_in[5];
    const float* b2  = (const float*)d_in[6];
    float* out = (float*)d_out;
    float* ws  = (float*)d_ws;
    unsigned* wsu = (unsigned*)d_ws;

    k_init<<<1, 256, 0, stream>>>(wsu, out);
    k_stats<<<NBLK, THR, 0, stream>>>(emb, wgt, gt, ws, wsu);
    k_centers<<<B, THR, 0, stream>>>(W1, b1, W2, b2, ws, wsu);
    k_hist<<<NBLK, THR, 0, stream>>>(emb, gt, W1, W2, b2, ws, wsu);
    k_reduce<<<64, 256, 0, stream>>>(wsu);
    k_loss<<<B, 256, 0, stream>>>(ws, wsu, out);
}